// Round 1
// baseline (1084.388 us; speedup 1.0000x reference)
//
#include <hip/hip_runtime.h>
#include <hip/hip_bf16.h>

// MoEMLPBlock: y = GELU(LN(sum_e coef[b,e]*(x @ w[e]^T) + coef@b))
// Strategy: single fused-K GEMM (M=16384,N=1024,K=8*1024) in split-bf16
// 3-term precision (fp32-class error ~1e-5), coef folded at expert
// boundaries, then fused bias+LN+GELU epilogue kernel.
// Workspace layout (needs >= 160 MiB):
//   [0,32M)    xh bf16 [16384][1024]
//   [32M,64M)  xl
//   [64M,80M)  wh bf16 [8][1024][1024]
//   [80M,96M)  wl
//   [96M,160M) ymid f32 [16384][1024]

typedef __attribute__((ext_vector_type(8))) short bf16x8;
typedef __attribute__((ext_vector_type(4))) float f32x4;

__device__ __forceinline__ unsigned short f2bf_rn(float f) {
    union { float f; unsigned u; } v; v.f = f;
    unsigned r = v.u + 0x7FFFu + ((v.u >> 16) & 1u);
    return (unsigned short)(r >> 16);
}
__device__ __forceinline__ float bf2f(unsigned short h) {
    union { unsigned u; float f; } v; v.u = ((unsigned)h) << 16; return v.f;
}

// ---------------- prep: split f32 -> bf16 hi + bf16 lo ----------------
__global__ __launch_bounds__(256) void split_f32_bf16(
        const float* __restrict__ in, unsigned short* __restrict__ hi,
        unsigned short* __restrict__ lo, int n4) {
    int i = blockIdx.x * blockDim.x + threadIdx.x;
    const int stride = gridDim.x * blockDim.x;
    for (; i < n4; i += stride) {
        float4 v = ((const float4*)in)[i];
        ushort4 h, l;
        h.x = f2bf_rn(v.x); l.x = f2bf_rn(v.x - bf2f(h.x));
        h.y = f2bf_rn(v.y); l.y = f2bf_rn(v.y - bf2f(h.y));
        h.z = f2bf_rn(v.z); l.z = f2bf_rn(v.z - bf2f(h.z));
        h.w = f2bf_rn(v.w); l.w = f2bf_rn(v.w - bf2f(h.w));
        ((ushort4*)hi)[i] = h;
        ((ushort4*)lo)[i] = l;
    }
}

// ---------------- GEMM: y[b,j] = sum_e coef[b,e] * sum_k x[b,k] w[e,j,k] ----
#define BM 256
#define BN 128
#define BK 32
#define NT 512

#define GLD(gp, lp) __builtin_amdgcn_global_load_lds( \
    (const __attribute__((address_space(1))) void*)(gp), \
    (__attribute__((address_space(3))) void*)(lp), 16, 0, 0)

__global__ __launch_bounds__(NT, 2) void gemm_moe(
        const unsigned short* __restrict__ xh, const unsigned short* __restrict__ xl,
        const unsigned short* __restrict__ wh, const unsigned short* __restrict__ wl,
        const float* __restrict__ coef, float* __restrict__ y) {
    __shared__ unsigned short As_h[BM * BK];  // 16 KB, row-major [256][32]
    __shared__ unsigned short As_l[BM * BK];
    __shared__ unsigned short Bs_h[BN * BK];  // 8 KB, row-major [128][32]
    __shared__ unsigned short Bs_l[BN * BK];

    const int bid = blockIdx.x;
    const int nb = bid & 7;        // column panel == XCD id (L2 locality)
    const int mb = bid >> 3;
    const int m0 = mb * BM, n0 = nb * BN;
    const int t = threadIdx.x;
    const int lane = t & 63;
    const int wid = t >> 6;
    const int wm = wid >> 1, wn = wid & 1;   // 4 x 2 wave grid, 64x64 tile each
    const int lr = lane & 15, kg = lane >> 4;

    // ---- staging source addressing (pre-swizzled global, linear LDS dest) --
    // LDS slot chunk cc' holds data chunk cc = cc' ^ (row & 3)  (bank swizzle)
    const int ar = t >> 2;                       // A rows 0..127 (+128 for 2nd)
    const int acs = (t & 3) ^ (ar & 3);
    const unsigned short* agh = xh + (size_t)(m0 + ar) * 1024 + acs * 8;
    const unsigned short* agl = xl + (size_t)(m0 + ar) * 1024 + acs * 8;
    const int br = t >> 2;                       // B rows 0..127
    const int bcs = (t & 3) ^ (br & 3);
    const size_t bofs = (size_t)(n0 + br) * 1024 + bcs * 8;

    // ---- fragment read offsets (swizzled, ushort units) ----
    int aoff[4], boff[4];
#pragma unroll
    for (int i = 0; i < 4; ++i) {
        int row = wm * 64 + i * 16 + lr;
        aoff[i] = row * BK + ((kg ^ (lr & 3)) * 8);
    }
#pragma unroll
    for (int j = 0; j < 4; ++j) {
        int row = wn * 64 + j * 16 + lr;
        boff[j] = row * BK + ((kg ^ (lr & 3)) * 8);
    }

    f32x4 acc_t[4][4] = {};

    for (int e = 0; e < 8; ++e) {
        f32x4 acc[4][4] = {};
        const unsigned short* wh_e = wh + (size_t)e * 1048576 + bofs;
        const unsigned short* wl_e = wl + (size_t)e * 1048576 + bofs;
#pragma unroll 1
        for (int kt = 0; kt < 1024 / BK; ++kt) {
            const int k = kt * BK;
            __syncthreads();
            // stage Ah, Al (2 x 16B chunks each), Bh, Bl (1 each)
            GLD(agh + k,          As_h + t * 8);
            GLD(agh + 131072 + k, As_h + 4096 + t * 8);
            GLD(agl + k,          As_l + t * 8);
            GLD(agl + 131072 + k, As_l + 4096 + t * 8);
            GLD(wh_e + k,         Bs_h + t * 8);
            GLD(wl_e + k,         Bs_l + t * 8);
            __syncthreads();

            bf16x8 ah[4], al[4], bh[4], bl[4];
#pragma unroll
            for (int i = 0; i < 4; ++i) {
                ah[i] = *(const bf16x8*)(As_h + aoff[i]);
                al[i] = *(const bf16x8*)(As_l + aoff[i]);
            }
#pragma unroll
            for (int j = 0; j < 4; ++j) {
                bh[j] = *(const bf16x8*)(Bs_h + boff[j]);
                bl[j] = *(const bf16x8*)(Bs_l + boff[j]);
            }
#pragma unroll
            for (int i = 0; i < 4; ++i)
#pragma unroll
                for (int j = 0; j < 4; ++j) {
                    acc[i][j] = __builtin_amdgcn_mfma_f32_16x16x32_bf16(
                        ah[i], bh[j], acc[i][j], 0, 0, 0);
                    acc[i][j] = __builtin_amdgcn_mfma_f32_16x16x32_bf16(
                        ah[i], bl[j], acc[i][j], 0, 0, 0);
                    acc[i][j] = __builtin_amdgcn_mfma_f32_16x16x32_bf16(
                        al[i], bh[j], acc[i][j], 0, 0, 0);
                }
        }
        // fold this expert's partial into the total with coef[m, e]
#pragma unroll
        for (int i = 0; i < 4; ++i) {
            const int mrow = m0 + wm * 64 + i * 16 + kg * 4;
#pragma unroll
            for (int r = 0; r < 4; ++r) {
                const float c = coef[(size_t)(mrow + r) * 8 + e];
#pragma unroll
                for (int j = 0; j < 4; ++j)
                    acc_t[i][j][r] += c * acc[i][j][r];
            }
        }
    }

    // C/D layout (verified m89): col = lane&15, row = (lane>>4)*4 + reg
#pragma unroll
    for (int i = 0; i < 4; ++i) {
        const int m = m0 + wm * 64 + i * 16 + kg * 4;
#pragma unroll
        for (int j = 0; j < 4; ++j) {
            const int n = n0 + wn * 64 + j * 16 + lr;
#pragma unroll
            for (int r = 0; r < 4; ++r)
                y[(size_t)(m + r) * 1024 + n] = acc_t[i][j][r];
        }
    }
}

// ---------------- fused bias + LayerNorm + exact GELU ----------------
__global__ __launch_bounds__(256) void ln_gelu(
        const float* __restrict__ y, const float* __restrict__ coef,
        const float* __restrict__ bexp, const float* __restrict__ gamma,
        const float* __restrict__ beta, float* __restrict__ out) {
    const int b = blockIdx.x;
    const int t = threadIdx.x;
    float4 v = ((const float4*)(y + (size_t)b * 1024))[t];

    float c[8];
#pragma unroll
    for (int e = 0; e < 8; ++e) c[e] = coef[(size_t)b * 8 + e];
    float bx = 0.f, by = 0.f, bz = 0.f, bw = 0.f;
#pragma unroll
    for (int e = 0; e < 8; ++e) {
        float4 w4 = ((const float4*)(bexp + (size_t)e * 1024))[t];
        bx += c[e] * w4.x; by += c[e] * w4.y;
        bz += c[e] * w4.z; bw += c[e] * w4.w;
    }
    v.x += bx; v.y += by; v.z += bz; v.w += bw;

    float s = v.x + v.y + v.z + v.w;
    float s2 = v.x * v.x + v.y * v.y + v.z * v.z + v.w * v.w;
#pragma unroll
    for (int off = 32; off >= 1; off >>= 1) {
        s  += __shfl_xor(s,  off);
        s2 += __shfl_xor(s2, off);
    }
    __shared__ float red[8];
    const int lane = t & 63, w = t >> 6;
    if (lane == 0) { red[w] = s; red[4 + w] = s2; }
    __syncthreads();
    s  = red[0] + red[1] + red[2] + red[3];
    s2 = red[4] + red[5] + red[6] + red[7];

    const float mu = s * (1.0f / 1024.0f);
    const float var = s2 * (1.0f / 1024.0f) - mu * mu;
    const float rstd = rsqrtf(var + 1e-5f);
    float4 g = ((const float4*)gamma)[t];
    float4 be = ((const float4*)beta)[t];
    float4 o;
    {
        float yy = (v.x - mu) * rstd * g.x + be.x;
        o.x = 0.5f * yy * (1.0f + erff(yy * 0.70710678118654752f));
        yy = (v.y - mu) * rstd * g.y + be.y;
        o.y = 0.5f * yy * (1.0f + erff(yy * 0.70710678118654752f));
        yy = (v.z - mu) * rstd * g.z + be.z;
        o.z = 0.5f * yy * (1.0f + erff(yy * 0.70710678118654752f));
        yy = (v.w - mu) * rstd * g.w + be.w;
        o.w = 0.5f * yy * (1.0f + erff(yy * 0.70710678118654752f));
    }
    ((float4*)(out + (size_t)b * 1024))[t] = o;
}

extern "C" void kernel_launch(void* const* d_in, const int* in_sizes, int n_in,
                              void* d_out, int out_size, void* d_ws, size_t ws_size,
                              hipStream_t stream) {
    (void)in_sizes; (void)n_in; (void)out_size; (void)ws_size;
    const float* x     = (const float*)d_in[0];
    const float* coef  = (const float*)d_in[1];
    const float* w     = (const float*)d_in[2];
    const float* bexp  = (const float*)d_in[3];
    const float* gamma = (const float*)d_in[4];
    const float* beta  = (const float*)d_in[5];
    float* out = (float*)d_out;

    unsigned short* xh = (unsigned short*)d_ws;
    unsigned short* xl = xh + 16777216;   // 16384*1024
    unsigned short* wh = xl + 16777216;
    unsigned short* wl = wh + 8388608;    // 8*1024*1024
    float* ymid = (float*)(wl + 8388608); // byte offset 100,663,296

    split_f32_bf16<<<2048, 256, 0, stream>>>(x, xh, xl, 16777216 / 4);
    split_f32_bf16<<<1024, 256, 0, stream>>>(w, wh, wl, 8388608 / 4);
    gemm_moe<<<512, NT, 0, stream>>>(xh, xl, wh, wl, coef, ymid);
    ln_gelu<<<16384, 256, 0, stream>>>(ymid, coef, bexp, gamma, beta, out);
}

// Round 3
// 969.916 us; speedup vs baseline: 1.1180x; 1.1180x over previous
//
#include <hip/hip_runtime.h>
#include <hip/hip_bf16.h>

// MoEMLPBlock: y = GELU(LN(sum_e coef[b,e]*(x @ w[e]^T) + coef@b))
// Split-bf16 3-term GEMM (fp32-class error), fused K = 8 experts x 1024.
// Round 2 (resubmit; round-2 bench never acquired a GPU):
// 32x32x16 MFMA + triple-buffered LDS + counted vmcnt(6) pipeline (T3+T4)
// + corrected (row>>1)&3 bank swizzle + setprio around MFMA.
// Workspace: [0,32M) xh | [32M,64M) xl | [64M,80M) wh | [80M,96M) wl | ymid f32

typedef __attribute__((ext_vector_type(8))) short bf16x8;
typedef __attribute__((ext_vector_type(16))) float f32x16;

__device__ __forceinline__ unsigned short f2bf_rn(float f) {
    union { float f; unsigned u; } v; v.f = f;
    unsigned r = v.u + 0x7FFFu + ((v.u >> 16) & 1u);
    return (unsigned short)(r >> 16);
}
__device__ __forceinline__ float bf2f(unsigned short h) {
    union { unsigned u; float f; } v; v.u = ((unsigned)h) << 16; return v.f;
}

// ---------------- prep: split f32 -> bf16 hi + bf16 lo ----------------
__global__ __launch_bounds__(256) void split_f32_bf16(
        const float* __restrict__ in, unsigned short* __restrict__ hi,
        unsigned short* __restrict__ lo, int n4) {
    int i = blockIdx.x * blockDim.x + threadIdx.x;
    const int stride = gridDim.x * blockDim.x;
    for (; i < n4; i += stride) {
        float4 v = ((const float4*)in)[i];
        ushort4 h, l;
        h.x = f2bf_rn(v.x); l.x = f2bf_rn(v.x - bf2f(h.x));
        h.y = f2bf_rn(v.y); l.y = f2bf_rn(v.y - bf2f(h.y));
        h.z = f2bf_rn(v.z); l.z = f2bf_rn(v.z - bf2f(h.z));
        h.w = f2bf_rn(v.w); l.w = f2bf_rn(v.w - bf2f(h.w));
        ((ushort4*)hi)[i] = h;
        ((ushort4*)lo)[i] = l;
    }
}

// ---------------- GEMM ----------------
// BM=256, BN=128, BK=32, 512 threads (8 waves, 4m x 2n of 64x64 wave-tiles,
// each = 2x2 of 32x32 MFMA tiles). LDS: 3 buffers x 48KB + 8KB coef table.
#define BUF_USH 24576   // per-buffer ushorts: Ah 8192 | Al 8192 | Bh 4096 | Bl 4096

#define GLD(gp, lp) __builtin_amdgcn_global_load_lds( \
    (const __attribute__((address_space(1))) void*)(gp), \
    (__attribute__((address_space(3))) void*)(lp), 16, 0, 0)

__global__ __launch_bounds__(512, 2) void gemm_moe(
        const unsigned short* __restrict__ xh, const unsigned short* __restrict__ xl,
        const unsigned short* __restrict__ wh, const unsigned short* __restrict__ wl,
        const float* __restrict__ coef, float* __restrict__ y) {
    __shared__ unsigned short S[3 * BUF_USH];   // 147456 B
    __shared__ float coef_s[2048];              // [256 rows][8 experts]

    const int bid = blockIdx.x;
    const int nb = bid & 7;          // n-panel == XCD (default RR dispatch)
    const int mb = bid >> 3;
    const int m0 = mb * 256, n0 = nb * 128;
    const int t = threadIdx.x;
    const int lane = t & 63;
    const int wid = t >> 6;
    const int wm = wid >> 1, wn = wid & 1;   // 4x2 waves of 64x64
    const int lr = lane & 31, hi = lane >> 5;

    // coef -> LDS (exactly 512 float4)
    ((float4*)coef_s)[t] = ((const float4*)(coef + (size_t)m0 * 8))[t];
    __syncthreads();   // drains vmcnt/lgkmcnt -> clean slate for counted waits

    // ---- staging: pre-swizzled global source, linear LDS dest ----
    // LDS slot (t&3) at row r holds global 16B-chunk (t&3)^((r>>1)&3)
    const int ar = t >> 2;                        // rows 0..127
    const int acs = (t & 3) ^ ((ar >> 1) & 3);
    const unsigned short* agh = xh + (size_t)(m0 + ar) * 1024 + acs * 8;
    const unsigned short* agl = xl + (size_t)(m0 + ar) * 1024 + acs * 8;
    const size_t bofs = (size_t)(n0 + ar) * 1024 + acs * 8;
    const unsigned short* wgh = wh + bofs;
    const unsigned short* wgl = wl + bofs;

    // ---- fragment read offsets (swizzled, ushort units) ----
    // 32x32x16 A/B operand: row = lane&31, k = (lane>>5)*8 + elem
    int aoff[2][2], boff[2][2];
#pragma unroll
    for (int i = 0; i < 2; ++i)
#pragma unroll
        for (int s = 0; s < 2; ++s) {
            const int slot = ((s << 1) + hi) ^ ((lr >> 1) & 3);
            aoff[i][s] = (wm * 64 + i * 32 + lr) * 32 + slot * 8;
            boff[i][s] = (wn * 64 + i * 32 + lr) * 32 + slot * 8;
        }

    f32x16 acc[2][2] = {};     // per-expert partial
    f32x16 acc_t[2][2] = {};   // coef-weighted total

    auto STAGE = [&](int kt2, int bufi) {
        unsigned short* bp = S + bufi * BUF_USH;
        const size_t eo = (size_t)(kt2 >> 5) << 20;   // expert * 1048576
        const int ko = (kt2 & 31) << 5;               // k-offset in x row
        GLD(agh + ko,           bp + t * 8);
        GLD(agh + 131072 + ko,  bp + 4096 + t * 8);   // rows 128..255
        GLD(agl + ko,           bp + 8192 + t * 8);
        GLD(agl + 131072 + ko,  bp + 12288 + t * 8);
        GLD(wgh + eo + ko,      bp + 16384 + t * 8);
        GLD(wgl + eo + ko,      bp + 20480 + t * 8);
    };

    STAGE(0, 0);
    STAGE(1, 1);
    asm volatile("s_waitcnt vmcnt(6)" ::: "memory");  // tile 0 landed
    __builtin_amdgcn_s_barrier();

    int cur = 0;
#pragma unroll 1
    for (int kt = 0; kt < 256; ++kt) {
        const unsigned short* bp = S + cur * BUF_USH;
        bf16x8 ah[2][2], al[2][2], bh2[2][2], bl2[2][2];
#pragma unroll
        for (int i = 0; i < 2; ++i)
#pragma unroll
            for (int s = 0; s < 2; ++s) {
                ah[i][s]  = *(const bf16x8*)(bp + aoff[i][s]);
                al[i][s]  = *(const bf16x8*)(bp + 8192 + aoff[i][s]);
                bh2[i][s] = *(const bf16x8*)(bp + 16384 + boff[i][s]);
                bl2[i][s] = *(const bf16x8*)(bp + 20480 + boff[i][s]);
            }
        if (kt < 254) {                       // stage tile kt+2
            int stg = cur + 2; if (stg >= 3) stg -= 3;
            STAGE(kt + 2, stg);
        }

        __builtin_amdgcn_s_setprio(1);
#pragma unroll
        for (int s = 0; s < 2; ++s)
#pragma unroll
            for (int i = 0; i < 2; ++i)
#pragma unroll
                for (int j = 0; j < 2; ++j) {
                    acc[i][j] = __builtin_amdgcn_mfma_f32_32x32x16_bf16(
                        ah[i][s], bh2[j][s], acc[i][j], 0, 0, 0);
                    acc[i][j] = __builtin_amdgcn_mfma_f32_32x32x16_bf16(
                        ah[i][s], bl2[j][s], acc[i][j], 0, 0, 0);
                    acc[i][j] = __builtin_amdgcn_mfma_f32_32x32x16_bf16(
                        al[i][s], bh2[j][s], acc[i][j], 0, 0, 0);
                }
        __builtin_amdgcn_s_setprio(0);

        if ((kt & 31) == 31) {                // expert boundary: coef fold
            const int e = kt >> 5;
#pragma unroll
            for (int i = 0; i < 2; ++i)
#pragma unroll
                for (int r = 0; r < 16; ++r) {
                    const int row = wm * 64 + i * 32 + (r & 3) + 8 * (r >> 2) + 4 * hi;
                    const float c = coef_s[row * 8 + e];
                    acc_t[i][0][r] += c * acc[i][0][r]; acc[i][0][r] = 0.f;
                    acc_t[i][1][r] += c * acc[i][1][r]; acc[i][1][r] = 0.f;
                }
        }

        // counted wait: tile kt+1's 6 loads done; kt+2's 6 stay in flight
        if (kt < 254) asm volatile("s_waitcnt vmcnt(6)" ::: "memory");
        else          asm volatile("s_waitcnt vmcnt(0)" ::: "memory");
        __builtin_amdgcn_s_barrier();
        cur = (cur == 2) ? 0 : cur + 1;
    }

    // C/D layout (m74/m101): col = lane&31, row = (r&3)+8*(r>>2)+4*(lane>>5)
#pragma unroll
    for (int i = 0; i < 2; ++i)
#pragma unroll
        for (int j = 0; j < 2; ++j) {
            const int n = n0 + wn * 64 + j * 32 + lr;
#pragma unroll
            for (int r = 0; r < 16; ++r) {
                const int m = m0 + wm * 64 + i * 32 + (r & 3) + 8 * (r >> 2) + 4 * hi;
                y[(size_t)m * 1024 + n] = acc_t[i][j][r];
            }
        }
}

// ---------------- fused bias + LayerNorm + exact GELU ----------------
__global__ __launch_bounds__(256) void ln_gelu(
        const float* __restrict__ y, const float* __restrict__ coef,
        const float* __restrict__ bexp, const float* __restrict__ gamma,
        const float* __restrict__ beta, float* __restrict__ out) {
    const int b = blockIdx.x;
    const int t = threadIdx.x;
    float4 v = ((const float4*)(y + (size_t)b * 1024))[t];

    float c[8];
#pragma unroll
    for (int e = 0; e < 8; ++e) c[e] = coef[(size_t)b * 8 + e];
    float bx = 0.f, by = 0.f, bz = 0.f, bw = 0.f;
#pragma unroll
    for (int e = 0; e < 8; ++e) {
        float4 w4 = ((const float4*)(bexp + (size_t)e * 1024))[t];
        bx += c[e] * w4.x; by += c[e] * w4.y;
        bz += c[e] * w4.z; bw += c[e] * w4.w;
    }
    v.x += bx; v.y += by; v.z += bz; v.w += bw;

    float s = v.x + v.y + v.z + v.w;
    float s2 = v.x * v.x + v.y * v.y + v.z * v.z + v.w * v.w;
#pragma unroll
    for (int off = 32; off >= 1; off >>= 1) {
        s  += __shfl_xor(s,  off);
        s2 += __shfl_xor(s2, off);
    }
    __shared__ float red[8];
    const int lane = t & 63, w = t >> 6;
    if (lane == 0) { red[w] = s; red[4 + w] = s2; }
    __syncthreads();
    s  = red[0] + red[1] + red[2] + red[3];
    s2 = red[4] + red[5] + red[6] + red[7];

    const float mu = s * (1.0f / 1024.0f);
    const float var = s2 * (1.0f / 1024.0f) - mu * mu;
    const float rstd = rsqrtf(var + 1e-5f);
    float4 g = ((const float4*)gamma)[t];
    float4 be = ((const float4*)beta)[t];
    float4 o;
    {
        float yy = (v.x - mu) * rstd * g.x + be.x;
        o.x = 0.5f * yy * (1.0f + erff(yy * 0.70710678118654752f));
        yy = (v.y - mu) * rstd * g.y + be.y;
        o.y = 0.5f * yy * (1.0f + erff(yy * 0.70710678118654752f));
        yy = (v.z - mu) * rstd * g.z + be.z;
        o.z = 0.5f * yy * (1.0f + erff(yy * 0.70710678118654752f));
        yy = (v.w - mu) * rstd * g.w + be.w;
        o.w = 0.5f * yy * (1.0f + erff(yy * 0.70710678118654752f));
    }
    ((float4*)(out + (size_t)b * 1024))[t] = o;
}

extern "C" void kernel_launch(void* const* d_in, const int* in_sizes, int n_in,
                              void* d_out, int out_size, void* d_ws, size_t ws_size,
                              hipStream_t stream) {
    (void)in_sizes; (void)n_in; (void)out_size; (void)ws_size;
    const float* x     = (const float*)d_in[0];
    const float* coef  = (const float*)d_in[1];
    const float* w     = (const float*)d_in[2];
    const float* bexp  = (const float*)d_in[3];
    const float* gamma = (const float*)d_in[4];
    const float* beta  = (const float*)d_in[5];
    float* out = (float*)d_out;

    unsigned short* xh = (unsigned short*)d_ws;
    unsigned short* xl = xh + 16777216;   // 16384*1024
    unsigned short* wh = xl + 16777216;
    unsigned short* wl = wh + 8388608;    // 8*1024*1024
    float* ymid = (float*)(wl + 8388608);

    split_f32_bf16<<<2048, 256, 0, stream>>>(x, xh, xl, 16777216 / 4);
    split_f32_bf16<<<1024, 256, 0, stream>>>(w, wh, wl, 8388608 / 4);
    gemm_moe<<<512, 512, 0, stream>>>(xh, xl, wh, wl, coef, ymid);
    ln_gelu<<<16384, 256, 0, stream>>>(ymid, coef, bexp, gamma, beta, out);
}